// Round 2
// baseline (1155.187 us; speedup 1.0000x reference)
//
#include <hip/hip_runtime.h>
#include <hip/hip_bf16.h>

// GCN->BiLSTM classifier pipeline on MI355X.
// Stages:
//  zero(H1), zero(seqs)
//  split W1^T, W2^T, Wih_f, Wih_b into bf16 hi/lo   (B operands for MFMA)
//  K1: B1t = split(X @ W1)^T                         [gemm, split-out]
//  K2: H1 += A @ B1                                  [gemm, split-K=4, atomics]
//  K3: B2t = split((H1+b1) @ W2)^T                   [gemm, biasA, split-out]
//  K4: seqs += A[token] @ B2                         [gemm, gather, split-K=8, atomics]
//  K5: xp = (seqs+b2) @ Wih^T + b_{f,b}              [gemm, gather(trip), dual-B, biasC]
//  K6: BiLSTM, 1 block per (dir,batch), Whh in VGPRs, h via v_readlane
//  K7: final FC -> out[64][4]
// All matmul precision via bf16 hi/lo split, 3 MFMA products (err ~2^-16 rel).
// R1 fix: B row offset must include n0 (K5's grid.z>1 loaded wrong gate rows).

typedef float f32x4 __attribute__((ext_vector_type(4)));
typedef __bf16 bf16x8 __attribute__((ext_vector_type(8)));
typedef unsigned short u16;
typedef unsigned int u32;

__device__ __forceinline__ u16 bf_hi_rn(float x, float& rem) {
    u32 u = __builtin_bit_cast(u32, x);
    u32 r = u + 0x7FFFu + ((u >> 16) & 1u);
    u16 h = (u16)(r >> 16);
    float hf = __builtin_bit_cast(float, (u32)h << 16);
    rem = x - hf;
    return h;
}
__device__ __forceinline__ u16 bf_trunc(float x) {
    return (u16)(__builtin_bit_cast(u32, x) >> 16);
}

__global__ void zero4_k(float4* p, int n4) {
    int i = blockIdx.x * 256 + threadIdx.x;
    if (i < n4) p[i] = make_float4(0.f, 0.f, 0.f, 0.f);
}

// split src into bf16 hi/lo, output layout [N][K]; trans: src is [K][N]
__global__ void split_k(const float* __restrict__ src, u16* __restrict__ hi,
                        u16* __restrict__ lo, int K, int N, int trans) {
    int id = blockIdx.x * 256 + threadIdx.x;
    if (id >= K * N) return;
    int n = id / K, k = id - n * K;
    float v = trans ? src[k * N + n] : src[id];
    float rem;
    u16 h = bf_hi_rn(v, rem);
    hi[id] = h;
    lo[id] = bf_trunc(rem);
}

// ---------------- universal split-bf16 MFMA GEMM ----------------
// C[M x N] = A_f32[M x K] * B_bf16split[N x K (transposed, ld=ldB)]
// GMODE: 0 = rows m0+i, 1 = rows tok[m0+i], 2 = seq-trip gather
template<int BM, int BN, int GMODE, int BIASA, int SPLITOUT, int ATOMIC, int BIASC, int DUAL>
__global__ __launch_bounds__(256, 2) void gemm_k(
    const float* __restrict__ A, int ldA,
    const u16* __restrict__ Bhi, const u16* __restrict__ Blo,
    const u16* __restrict__ Bhi2, const u16* __restrict__ Blo2, int ldB,
    float* __restrict__ C, int ldC,
    u16* __restrict__ Chi, u16* __restrict__ Clo, int ldCT,
    const float* __restrict__ biasA,
    const float* __restrict__ biasC, const float* __restrict__ biasC2,
    const int* __restrict__ tok,
    int kchunk, int Mhalf)
{
    constexpr int BK = 32;
    constexpr int AF = BM * 32 / 256;   // fp32 elems of A staged per thread
    constexpr int TPR_A = 32 / AF;
    constexpr int BF = BN * 32 / 256;   // u16 elems per plane of B per thread
    constexpr int TPR_B = 32 / BF;

    const int t = threadIdx.x;
    const int lane = t & 63, wv = t >> 6;
    const int m0 = blockIdx.x * BM;
    const int n0 = blockIdx.z * BN;
    const int kbeg = blockIdx.y * kchunk;

    const int wm0 = (BM == 64) ? 0 : (wv >> 1) * 64;
    const int wn0 = (BM == 64) ? wv * 64 : (wv & 1) * 64;

    __shared__ alignas(16) u16 sAhi[BM][40];
    __shared__ alignas(16) u16 sAlo[BM][40];
    __shared__ alignas(16) u16 sBhi[BN][40];
    __shared__ alignas(16) u16 sBlo[BN][40];
    __shared__ int sRow[BM];

    if (t < BM) {
        int r;
        if (GMODE == 0) r = m0 + t;
        else if (GMODE == 1) r = tok[m0 + t];
        else {
            int trip = m0 + t;
            int rem = trip & (Mhalf - 1);
            int l = rem >> 6, b = rem & 63;
            r = (trip < Mhalf) ? (b * 64 + l) : (b * 64 + (63 - l));
        }
        sRow[t] = r;
    }
    __syncthreads();

    const bool second = DUAL && (m0 >= Mhalf);
    const u16* __restrict__ bh = second ? Bhi2 : Bhi;
    const u16* __restrict__ bl = second ? Blo2 : Blo;

    const int arow = t / TPR_A;
    const int acol0 = (t % TPR_A) * AF;
    const int brow = t / TPR_B;
    const int bcol0 = (t % TPR_B) * BF;
    const size_t aRowOff = (size_t)sRow[arow] * ldA;
    const size_t bRowOffH = (size_t)(n0 + brow) * ldB;   // R1 fix: include n0

    f32x4 acc[4][4];
#pragma unroll
    for (int i = 0; i < 4; i++)
#pragma unroll
        for (int j = 0; j < 4; j++) acc[i][j] = (f32x4){0.f, 0.f, 0.f, 0.f};

    const int fm = lane & 15, fq = lane >> 4;

    for (int kc = kbeg; kc < kbeg + kchunk; kc += BK) {
        // ---- global loads ----
        float av[AF];
#pragma unroll
        for (int i = 0; i < AF; i += 4) {
            float4 v = *(const float4*)(A + aRowOff + kc + acol0 + i);
            av[i] = v.x; av[i + 1] = v.y; av[i + 2] = v.z; av[i + 3] = v.w;
        }
        if (BIASA) {
#pragma unroll
            for (int i = 0; i < AF; i += 4) {
                float4 bv = *(const float4*)(biasA + kc + acol0 + i);
                av[i] += bv.x; av[i + 1] += bv.y; av[i + 2] += bv.z; av[i + 3] += bv.w;
            }
        }
        uint4 bvh[BF / 8], bvl[BF / 8];
        {
            const u16* p0 = bh + bRowOffH + kc + bcol0;
            const u16* p1 = bl + bRowOffH + kc + bcol0;
#pragma unroll
            for (int j = 0; j < BF / 8; j++) {
                bvh[j] = *(const uint4*)(p0 + j * 8);
                bvl[j] = *(const uint4*)(p1 + j * 8);
            }
        }
        __syncthreads();   // previous iter's LDS reads complete
        // ---- convert + store A ----
#pragma unroll
        for (int i = 0; i < AF; i += 8) {
            u32 ph[4], pl[4];
#pragma unroll
            for (int q = 0; q < 4; q++) {
                float r0, r1;
                u32 h0 = bf_hi_rn(av[i + 2 * q], r0);
                u32 h1 = bf_hi_rn(av[i + 2 * q + 1], r1);
                ph[q] = h0 | (h1 << 16);
                pl[q] = (u32)bf_trunc(r0) | ((u32)bf_trunc(r1) << 16);
            }
            *(uint4*)&sAhi[arow][acol0 + i] = make_uint4(ph[0], ph[1], ph[2], ph[3]);
            *(uint4*)&sAlo[arow][acol0 + i] = make_uint4(pl[0], pl[1], pl[2], pl[3]);
        }
        // ---- store B ----
#pragma unroll
        for (int j = 0; j < BF / 8; j++) {
            *(uint4*)&sBhi[brow][bcol0 + j * 8] = bvh[j];
            *(uint4*)&sBlo[brow][bcol0 + j * 8] = bvl[j];
        }
        __syncthreads();
        // ---- fragments + MFMA ----
        bf16x8 bhf[4], blf[4];
#pragma unroll
        for (int j = 0; j < 4; j++) {
            bhf[j] = *(const bf16x8*)&sBhi[wn0 + j * 16 + fm][fq * 8];
            blf[j] = *(const bf16x8*)&sBlo[wn0 + j * 16 + fm][fq * 8];
        }
#pragma unroll
        for (int i = 0; i < 4; i++) {
            bf16x8 ah = *(const bf16x8*)&sAhi[wm0 + i * 16 + fm][fq * 8];
            bf16x8 al = *(const bf16x8*)&sAlo[wm0 + i * 16 + fm][fq * 8];
#pragma unroll
            for (int j = 0; j < 4; j++) {
                acc[i][j] = __builtin_amdgcn_mfma_f32_16x16x32_bf16(ah, bhf[j], acc[i][j], 0, 0, 0);
                acc[i][j] = __builtin_amdgcn_mfma_f32_16x16x32_bf16(ah, blf[j], acc[i][j], 0, 0, 0);
                acc[i][j] = __builtin_amdgcn_mfma_f32_16x16x32_bf16(al, bhf[j], acc[i][j], 0, 0, 0);
            }
        }
    }

    // ---- epilogue ----
    if (ATOMIC) {
#pragma unroll
        for (int i = 0; i < 4; i++)
#pragma unroll
            for (int j = 0; j < 4; j++)
#pragma unroll
                for (int r = 0; r < 4; r++) {
                    int row = m0 + wm0 + i * 16 + fq * 4 + r;
                    int col = n0 + wn0 + j * 16 + fm;
                    atomicAdd(&C[(size_t)row * ldC + col], acc[i][j][r]);
                }
    } else if (!SPLITOUT) {
        const float* bc = second ? biasC2 : biasC;
#pragma unroll
        for (int i = 0; i < 4; i++)
#pragma unroll
            for (int j = 0; j < 4; j++)
#pragma unroll
                for (int r = 0; r < 4; r++) {
                    int row = m0 + wm0 + i * 16 + fq * 4 + r;
                    int col = n0 + wn0 + j * 16 + fm;
                    float v = acc[i][j][r];
                    if (BIASC) v += bc[col];
                    C[(size_t)row * ldC + col] = v;
                }
    } else {
        // transposed split-bf16 output via LDS scratch (overlays sBhi)
        float* scr = (float*)&sBhi[0][0];
        constexpr int SEG = 256 / BN;      // 1 (BN=256) or 2 (BN=128)
        constexpr int RPT = 16 / SEG;      // rows per thread
        const int col = t % BN, mseg = t / BN;
#pragma unroll 1
        for (int gmt = 0; gmt < BM / 16; gmt++) {
            __syncthreads();
            if (gmt * 16 >= wm0 && gmt * 16 < wm0 + 64) {
                int i = (gmt * 16 - wm0) >> 4;
#pragma unroll
                for (int j = 0; j < 4; j++)
#pragma unroll
                    for (int r = 0; r < 4; r++)
                        scr[(fq * 4 + r) * BN + wn0 + j * 16 + fm] = acc[i][j][r];
            }
            __syncthreads();
            u16 oh[RPT], ol[RPT];
#pragma unroll
            for (int q = 0; q < RPT; q++) {
                float v = scr[(mseg * RPT + q) * BN + col];
                float rem;
                oh[q] = bf_hi_rn(v, rem);
                ol[q] = bf_trunc(rem);
            }
            size_t off = (size_t)(n0 + col) * ldCT + m0 + gmt * 16 + mseg * RPT;
#pragma unroll
            for (int q = 0; q < RPT; q += 8) {
                *(uint4*)(Chi + off + q) = make_uint4(
                    (u32)oh[q] | ((u32)oh[q + 1] << 16), (u32)oh[q + 2] | ((u32)oh[q + 3] << 16),
                    (u32)oh[q + 4] | ((u32)oh[q + 5] << 16), (u32)oh[q + 6] | ((u32)oh[q + 7] << 16));
                *(uint4*)(Clo + off + q) = make_uint4(
                    (u32)ol[q] | ((u32)ol[q + 1] << 16), (u32)ol[q + 2] | ((u32)ol[q + 3] << 16),
                    (u32)ol[q + 4] | ((u32)ol[q + 5] << 16), (u32)ol[q + 6] | ((u32)ol[q + 7] << 16));
            }
        }
    }
}

// ---------------- BiLSTM ----------------
__device__ __forceinline__ float rl(float v, int l) {
    return __builtin_bit_cast(float, __builtin_amdgcn_readlane(__builtin_bit_cast(int, v), l));
}
__device__ __forceinline__ float fsigmoid(float x) { return 1.f / (1.f + __expf(-x)); }
__device__ __forceinline__ float ftanh(float x) {
    float e = __expf(2.f * x);
    return 1.f - 2.f / (e + 1.f);
}

__global__ __launch_bounds__(512, 2) void lstm_k(
    const float* __restrict__ xp,       // [2][64(l)][64(b)][512]
    const float* __restrict__ Whh_f, const float* __restrict__ Whh_b,
    const int* __restrict__ lengths,
    float* __restrict__ hfin)           // [2][64][128]
{
    const int bid = blockIdx.x;         // 0..127
    const int dir = bid >> 6;
    const int b = bid & 63;
    const int t = threadIdx.x;          // gate row g
    const int lane = t & 63, wv = t >> 6;
    const int gtype = wv >> 1;          // 0=i 1=f 2=g 3=o
    const float* Whh = dir ? Whh_b : Whh_f;
    const int len = lengths[b];

    float wr[128];
#pragma unroll
    for (int i = 0; i < 128; i += 4) {
        float4 v = *(const float4*)(Whh + t * 128 + i);
        wr[i] = v.x; wr[i + 1] = v.y; wr[i + 2] = v.z; wr[i + 3] = v.w;
    }

    __shared__ float gact[2][512];
    float h0 = 0.f, h1 = 0.f, c0 = 0.f, c1 = 0.f;
    const float* xpp = xp + ((size_t)dir * 4096 + b) * 512 + t;  // + l*64*512

    for (int l = 0; l < 64; l++) {
        float xg = xpp[(size_t)l * 32768];
        float a0 = xg, a1 = 0.f, a2 = 0.f, a3 = 0.f;
#pragma unroll
        for (int j = 0; j < 64; j += 2) {
            a0 = fmaf(wr[j], rl(h0, j), a0);
            a1 = fmaf(wr[j + 1], rl(h0, j + 1), a1);
        }
#pragma unroll
        for (int j = 0; j < 64; j += 2) {
            a2 = fmaf(wr[64 + j], rl(h1, j), a2);
            a3 = fmaf(wr[64 + j + 1], rl(h1, j + 1), a3);
        }
        float acc = (a0 + a1) + (a2 + a3);
        float act = (gtype == 2) ? ftanh(acc) : fsigmoid(acc);
        gact[l & 1][t] = act;
        __syncthreads();
        float iv0 = gact[l & 1][lane],       iv1 = gact[l & 1][64 + lane];
        float fv0 = gact[l & 1][128 + lane], fv1 = gact[l & 1][192 + lane];
        float gv0 = gact[l & 1][256 + lane], gv1 = gact[l & 1][320 + lane];
        float ov0 = gact[l & 1][384 + lane], ov1 = gact[l & 1][448 + lane];
        float cn0 = fv0 * c0 + iv0 * gv0;
        float cn1 = fv1 * c1 + iv1 * gv1;
        float hn0 = ov0 * ftanh(cn0);
        float hn1 = ov1 * ftanh(cn1);
        bool upd = ((dir == 0) ? l : (63 - l)) < len;
        if (upd) { c0 = cn0; c1 = cn1; h0 = hn0; h1 = hn1; }
    }
    if (wv == 0) {
        hfin[((size_t)dir * 64 + b) * 128 + lane] = h0;
        hfin[((size_t)dir * 64 + b) * 128 + 64 + lane] = h1;
    }
}

__global__ void fc_k(const float* __restrict__ hf, const float* __restrict__ Wfc,
                     const float* __restrict__ bfc, float* __restrict__ out) {
    int t = threadIdx.x;        // 256
    int b = t >> 2, c = t & 3;
    float s = bfc[c];
#pragma unroll 4
    for (int j = 0; j < 128; j++) s = fmaf(hf[b * 128 + j], Wfc[c * 256 + j], s);
#pragma unroll 4
    for (int j = 0; j < 128; j++) s = fmaf(hf[(64 + b) * 128 + j], Wfc[c * 256 + 128 + j], s);
    out[b * 4 + c] = s;
}

extern "C" void kernel_launch(void* const* d_in, const int* in_sizes, int n_in,
                              void* d_out, int out_size, void* d_ws, size_t ws_size,
                              hipStream_t stream) {
    const float* A     = (const float*)d_in[0];
    const float* X     = (const float*)d_in[1];
    const int*   tok   = (const int*)d_in[2];
    const int*   lens  = (const int*)d_in[3];
    const float* W1    = (const float*)d_in[4];
    const float* b1    = (const float*)d_in[5];
    const float* W2    = (const float*)d_in[6];
    const float* b2    = (const float*)d_in[7];
    const float* Wih_f = (const float*)d_in[8];
    const float* Whh_f = (const float*)d_in[9];
    const float* b_f   = (const float*)d_in[10];
    const float* Wih_b = (const float*)d_in[11];
    const float* Whh_b = (const float*)d_in[12];
    const float* b_b   = (const float*)d_in[13];
    const float* Wfc   = (const float*)d_in[14];
    const float* bfc   = (const float*)d_in[15];
    float* out = (float*)d_out;
    char* ws = (char*)d_ws;

    u16*   B1hi = (u16*)(ws + 0);               // [256][8192]
    u16*   B1lo = (u16*)(ws + 4194304);
    float* H1   = (float*)(ws + 8388608);       // [8192][256]
    u16*   B2hi = (u16*)(ws + 16777216);        // [128][8192]
    u16*   B2lo = (u16*)(ws + 18874368);
    float* seqs = (float*)(ws + 20971520);      // [4096][128]
    float* xp   = (float*)(ws + 23068672);      // [2][64][64][512]
    float* hfin = (float*)(ws + 39845888);      // [2][64][128]
    u16*   W1hi = (u16*)(ws + 39911424);        // [256][256]
    u16*   W1lo = (u16*)(ws + 40042496);
    u16*   W2hi = (u16*)(ws + 40173568);        // [128][256]
    u16*   W2lo = (u16*)(ws + 40239104);
    u16*   Wfh  = (u16*)(ws + 40304640);        // [512][128]
    u16*   Wfl  = (u16*)(ws + 40435712);
    u16*   Wbh  = (u16*)(ws + 40566784);
    u16*   Wbl  = (u16*)(ws + 40697856);

    zero4_k<<<2048, 256, 0, stream>>>((float4*)H1, 524288);
    zero4_k<<<512, 256, 0, stream>>>((float4*)seqs, 131072);
    split_k<<<256, 256, 0, stream>>>(W1, W1hi, W1lo, 256, 256, 1);
    split_k<<<128, 256, 0, stream>>>(W2, W2hi, W2lo, 256, 128, 1);
    split_k<<<256, 256, 0, stream>>>(Wih_f, Wfh, Wfl, 128, 512, 0);
    split_k<<<256, 256, 0, stream>>>(Wih_b, Wbh, Wbl, 128, 512, 0);

    // K1: B1t = split(X @ W1)^T
    gemm_k<64, 256, 0, 0, 1, 0, 0, 0><<<dim3(128, 1, 1), 256, 0, stream>>>(
        X, 256, W1hi, W1lo, nullptr, nullptr, 256,
        nullptr, 0, B1hi, B1lo, 8192, nullptr, nullptr, nullptr, nullptr, 256, 4096);
    // K2: H1 += A @ B1   (split-K = 4)
    gemm_k<64, 256, 0, 0, 0, 1, 0, 0><<<dim3(128, 4, 1), 256, 0, stream>>>(
        A, 8192, B1hi, B1lo, nullptr, nullptr, 8192,
        H1, 256, nullptr, nullptr, 0, nullptr, nullptr, nullptr, nullptr, 2048, 4096);
    // K3: B2t = split((H1+b1) @ W2)^T
    gemm_k<128, 128, 0, 1, 1, 0, 0, 0><<<dim3(64, 1, 1), 256, 0, stream>>>(
        H1, 256, W2hi, W2lo, nullptr, nullptr, 256,
        nullptr, 0, B2hi, B2lo, 8192, b1, nullptr, nullptr, nullptr, 256, 4096);
    // K4: seqs += A[token] @ B2   (split-K = 8)
    gemm_k<128, 128, 1, 0, 0, 1, 0, 0><<<dim3(32, 8, 1), 256, 0, stream>>>(
        A, 8192, B2hi, B2lo, nullptr, nullptr, 8192,
        seqs, 128, nullptr, nullptr, 0, nullptr, nullptr, nullptr, tok, 1024, 4096);
    // K5: xp = (seqs+b2) @ Wih^T + b   (dual fwd/bwd, N=512 via z-split)
    gemm_k<128, 128, 2, 1, 0, 0, 1, 1><<<dim3(64, 1, 4), 256, 0, stream>>>(
        seqs, 128, Wfh, Wfl, Wbh, Wbl, 128,
        xp, 512, nullptr, nullptr, 0, b2, b_f, b_b, nullptr, 128, 4096);
    // K6: BiLSTM
    lstm_k<<<128, 512, 0, stream>>>(xp, Whh_f, Whh_b, lens, hfin);
    // K7: final FC
    fc_k<<<1, 256, 0, stream>>>(hfin, Wfc, bfc, out);
}

// Round 3
// 817.247 us; speedup vs baseline: 1.4135x; 1.4135x over previous
//
#include <hip/hip_runtime.h>
#include <hip/hip_bf16.h>

// GCN->BiLSTM classifier on MI355X — R3: restructured GEMM.
//  - All MFMA B operands pre-stored in chunk-contiguous swizzled layout
//    [K/32][N][32 u16], granule g (8 u16) at position p = g ^ ((n>>1)&3)
//    -> global_load_lds width-16 streams tiles straight to LDS, and MFMA
//    fragment ds_read_b128 is 2-way-conflict-free (free on CDNA4).
//  - gemm2_k: 512 thr, BM=256 x BN=128, BK=32, double-buffered LDS,
//    B via async global_load_lds, A fp32 loaded to regs + converted to
//    bf16 hi/lo (3-product split) + ds_write, prefetch distance 1.
//  - No atomics: split-K writes per-slice partials; consumer sums them
//    during its A-load (K3 sums 4 H1 partials, K5 sums 16 seqs partials).
// Pipeline: wsplit(W1,W2,Wih) -> K1 (X@W1 -> B1 swizzled) -> K2 (A@B1 ->
// H1p x4) -> K3 (sum+b1 @W2 -> B2 swizzled) -> K4 (A[tok]@B2 -> seqsP x16)
// -> K5 (sum+b2 @Wih^T +b -> xp, dual fwd/bwd) -> lstm -> fc.

typedef float f32x4 __attribute__((ext_vector_type(4)));
typedef __bf16 bf16x8 __attribute__((ext_vector_type(8)));
typedef unsigned short u16;
typedef unsigned int u32;

__device__ __forceinline__ u16 bf_hi_rn(float x, float& rem) {
    u32 u = __builtin_bit_cast(u32, x);
    u32 r = u + 0x7FFFu + ((u >> 16) & 1u);
    u16 h = (u16)(r >> 16);
    float hf = __builtin_bit_cast(float, (u32)h << 16);
    rem = x - hf;
    return h;
}
__device__ __forceinline__ u16 bf_trunc(float x) {
    return (u16)(__builtin_bit_cast(u32, x) >> 16);
}
__device__ __forceinline__ void pack8(const float* v, uint4& H, uint4& L) {
    u32 h[4], l[4];
#pragma unroll
    for (int q = 0; q < 4; q++) {
        float r0, r1;
        u32 h0 = bf_hi_rn(v[2 * q], r0);
        u32 h1 = bf_hi_rn(v[2 * q + 1], r1);
        h[q] = h0 | (h1 << 16);
        l[q] = (u32)bf_trunc(r0) | ((u32)bf_trunc(r1) << 16);
    }
    H = make_uint4(h[0], h[1], h[2], h[3]);
    L = make_uint4(l[0], l[1], l[2], l[3]);
}

__device__ __forceinline__ void glds16(const u16* g, u16* l) {
    __builtin_amdgcn_global_load_lds(
        (const __attribute__((address_space(1))) void*)g,
        (__attribute__((address_space(3))) void*)l, 16, 0, 0);
}

// ---- weight split into swizzled B layout [K/32][N][32] ----
template<int TRANS>   // TRANS=1: W is [K][N]; TRANS=0: W is [N][K]
__global__ void wsplit_k(const float* __restrict__ W, u16* __restrict__ hi,
                         u16* __restrict__ lo, int K, int N) {
    int gid = blockIdx.x * 256 + threadIdx.x;
    int total = (K >> 5) * N * 4;
    if (gid >= total) return;
    int g = gid & 3, n = (gid >> 2) % N, kc = gid / (4 * N);
    float v[8];
#pragma unroll
    for (int e = 0; e < 8; e++) {
        int k = kc * 32 + g * 8 + e;
        v[e] = TRANS ? W[(size_t)k * N + n] : W[(size_t)n * K + k];
    }
    uint4 H, L;
    pack8(v, H, L);
    int p = g ^ ((n >> 1) & 3);
    size_t off = ((size_t)kc * N + n) * 32 + p * 8;
    *(uint4*)(hi + off) = H;
    *(uint4*)(lo + off) = L;
}

// ---------------- split-bf16 MFMA GEMM, dbuf + global_load_lds ----------------
// C[M x N] = (sum_p A_p)[M x K] * B[N x K], B in swizzled chunk layout.
template<int GMODE, int NPART, int BIASA, int SPLITOUT, int BIASC, int DUAL>
__global__ __launch_bounds__(512, 1) void gemm2_k(
    const float* __restrict__ A, int ldA, int Mtot,
    const u16* __restrict__ Bhi, const u16* __restrict__ Blo,
    const u16* __restrict__ Bhi2, const u16* __restrict__ Blo2, int Nfull,
    float* __restrict__ C, int ldC, long partStride,
    u16* __restrict__ Chi, u16* __restrict__ Clo, int Nout,
    const float* __restrict__ biasA,
    const float* __restrict__ biasC, const float* __restrict__ biasC2,
    const int* __restrict__ tok, int kchunk, int Mhalf)
{
    constexpr int BM = 256, BN = 128;
    const int t = threadIdx.x;
    const int lane = t & 63, wv = t >> 6;
    const int fm = lane & 15, fq = lane >> 4;
    const int wm0 = (wv >> 1) * 64, wn0 = (wv & 1) * 64;
    const int m0 = blockIdx.x * BM;
    const int n0 = blockIdx.z * BN;
    const int kbeg = blockIdx.y * kchunk;

    __shared__ alignas(16) u16 sAhi[2][BM * 32];
    __shared__ alignas(16) u16 sAlo[2][BM * 32];
    __shared__ alignas(16) u16 sBhi[2][BN * 32];
    __shared__ alignas(16) u16 sBlo[2][BN * 32];
    __shared__ int sRow[BM];

    if (t < BM) {
        int r;
        if (GMODE == 0) r = m0 + t;
        else if (GMODE == 1) r = tok[m0 + t];
        else {
            int trip = m0 + t;
            int rem = trip & (Mhalf - 1);
            int l = rem >> 6, b = rem & 63;
            r = (trip < Mhalf) ? (b * 64 + l) : (b * 64 + (63 - l));
        }
        sRow[t] = r;
    }
    __syncthreads();

    const bool second = DUAL && (m0 >= Mhalf);
    const u16* __restrict__ bhp = second ? Bhi2 : Bhi;
    const u16* __restrict__ blp = second ? Blo2 : Blo;

    // A staging: thread owns row r=t>>1, cols half*16..+15
    const int r = t >> 1, half = t & 1, co = half * 16;
    const int sw = (r >> 1) & 3;
    const int p0 = (2 * half) ^ sw, p1 = (2 * half + 1) ^ sw;
    const float* Abase = A + (size_t)sRow[r] * ldA + co;
    const size_t pstep = (size_t)Mtot * ldA;

    // B DMA pointers (chunk-contiguous)
    const size_t bstep = (size_t)Nfull * 32;
    const u16* gbh = bhp + ((size_t)(kbeg >> 5) * Nfull + n0) * 32 + t * 8;
    const u16* gbl = blp + ((size_t)(kbeg >> 5) * Nfull + n0) * 32 + t * 8;
    u16* ldsBh0 = &sBhi[0][wv * 512];
    u16* ldsBl0 = &sBlo[0][wv * 512];
    u16* ldsBh1 = &sBhi[1][wv * 512];
    u16* ldsBl1 = &sBlo[1][wv * 512];

    f32x4 acc[4][4];
#pragma unroll
    for (int i = 0; i < 4; i++)
#pragma unroll
        for (int j = 0; j < 4; j++) acc[i][j] = (f32x4){0.f, 0.f, 0.f, 0.f};

    float av[16];
    auto loadA = [&](int kk) {
#pragma unroll
        for (int c = 0; c < 16; c += 4) {
            float4 s = *(const float4*)(Abase + kk + c);
            av[c] = s.x; av[c + 1] = s.y; av[c + 2] = s.z; av[c + 3] = s.w;
        }
#pragma unroll
        for (int p = 1; p < NPART; p++) {
#pragma unroll
            for (int c = 0; c < 16; c += 4) {
                float4 s = *(const float4*)(Abase + (size_t)p * pstep + kk + c);
                av[c] += s.x; av[c + 1] += s.y; av[c + 2] += s.z; av[c + 3] += s.w;
            }
        }
        if (BIASA) {
#pragma unroll
            for (int c = 0; c < 16; c += 4) {
                float4 s = *(const float4*)(biasA + kk + co + c);
                av[c] += s.x; av[c + 1] += s.y; av[c + 2] += s.z; av[c + 3] += s.w;
            }
        }
    };
    auto storeA = [&](int nb) {
        uint4 H0, L0, H1, L1;
        pack8(av, H0, L0);
        pack8(av + 8, H1, L1);
        int base = r * 32;
        *(uint4*)&sAhi[nb][base + p0 * 8] = H0;
        *(uint4*)&sAlo[nb][base + p0 * 8] = L0;
        *(uint4*)&sAhi[nb][base + p1 * 8] = H1;
        *(uint4*)&sAlo[nb][base + p1 * 8] = L1;
    };
    const int pf8 = (fq ^ ((fm >> 1) & 3)) * 8;
    auto compute = [&](int cur) {
        bf16x8 bh4[4], bl4[4];
#pragma unroll
        for (int j = 0; j < 4; j++) {
            int off = (wn0 + 16 * j + fm) * 32 + pf8;
            bh4[j] = *(const bf16x8*)&sBhi[cur][off];
            bl4[j] = *(const bf16x8*)&sBlo[cur][off];
        }
#pragma unroll
        for (int i = 0; i < 4; i++) {
            int off = (wm0 + 16 * i + fm) * 32 + pf8;
            bf16x8 ah = *(const bf16x8*)&sAhi[cur][off];
            bf16x8 al = *(const bf16x8*)&sAlo[cur][off];
#pragma unroll
            for (int j = 0; j < 4; j++) {
                acc[i][j] = __builtin_amdgcn_mfma_f32_16x16x32_bf16(ah, bh4[j], acc[i][j], 0, 0, 0);
                acc[i][j] = __builtin_amdgcn_mfma_f32_16x16x32_bf16(ah, bl4[j], acc[i][j], 0, 0, 0);
                acc[i][j] = __builtin_amdgcn_mfma_f32_16x16x32_bf16(al, bh4[j], acc[i][j], 0, 0, 0);
            }
        }
    };

    const int iters = kchunk >> 5;
    // prologue: fill buffer 0
    glds16(gbh, ldsBh0);
    glds16(gbl, ldsBl0);
    loadA(kbeg);
    storeA(0);
    __syncthreads();

#pragma unroll 1
    for (int k = 0; k < iters; k++) {
        const int cur = k & 1, nb = cur ^ 1;
        const bool pf = (k + 1 < iters);
        if (pf) {
            glds16(gbh + (size_t)(k + 1) * bstep, nb ? ldsBh1 : ldsBh0);
            glds16(gbl + (size_t)(k + 1) * bstep, nb ? ldsBl1 : ldsBl0);
            loadA(kbeg + (k + 1) * 32);
        }
        compute(cur);
        if (pf) storeA(nb);
        __syncthreads();
    }

    if (!SPLITOUT) {
        float* Cp = C + (size_t)blockIdx.y * partStride;
        const float* bc = second ? biasC2 : biasC;
#pragma unroll
        for (int i = 0; i < 4; i++)
#pragma unroll
            for (int j = 0; j < 4; j++)
#pragma unroll
                for (int rr = 0; rr < 4; rr++) {
                    int row = m0 + wm0 + 16 * i + fq * 4 + rr;
                    int col = n0 + wn0 + 16 * j + fm;
                    float v = acc[i][j][rr];
                    if (BIASC) v += bc[col];
                    Cp[(size_t)row * ldC + col] = v;
                }
    } else {
        // transposed swizzled-split output: C tile rows become B-layout k-chunks
        float* scr = (float*)&sAhi[0][0];       // 32 x BN fp32 = 16 KB scratch
        const int kc0 = m0 >> 5;
        const int n = t & (BN - 1), gs = t >> 7;   // gs in 0..3
        const int ngl = n0 + n;
        const int pp = gs ^ ((ngl >> 1) & 3);
#pragma unroll 1
        for (int g8 = 0; g8 < BM / 32; g8++) {
            if ((wv >> 1) == (g8 >> 1)) {
                int ib = (g8 & 1) * 2;
#pragma unroll
                for (int i2 = 0; i2 < 2; i2++)
#pragma unroll
                    for (int j = 0; j < 4; j++)
#pragma unroll
                        for (int rr = 0; rr < 4; rr++)
                            scr[(i2 * 16 + fq * 4 + rr) * BN + wn0 + 16 * j + fm] =
                                acc[ib + i2][j][rr];
            }
            __syncthreads();
            float v[8];
#pragma unroll
            for (int e = 0; e < 8; e++) v[e] = scr[(gs * 8 + e) * BN + n];
            uint4 H, L;
            pack8(v, H, L);
            size_t off = ((size_t)(kc0 + g8) * Nout + ngl) * 32 + pp * 8;
            *(uint4*)(Chi + off) = H;
            *(uint4*)(Clo + off) = L;
            __syncthreads();
        }
    }
}

// ---------------- BiLSTM ----------------
__device__ __forceinline__ float rl(float v, int l) {
    return __builtin_bit_cast(float, __builtin_amdgcn_readlane(__builtin_bit_cast(int, v), l));
}
__device__ __forceinline__ float fsigmoid(float x) { return 1.f / (1.f + __expf(-x)); }
__device__ __forceinline__ float ftanh(float x) {
    float e = __expf(2.f * x);
    return 1.f - 2.f / (e + 1.f);
}

__global__ __launch_bounds__(512, 2) void lstm_k(
    const float* __restrict__ xp,       // [2][64(l)][64(b)][512]
    const float* __restrict__ Whh_f, const float* __restrict__ Whh_b,
    const int* __restrict__ lengths,
    float* __restrict__ hfin)           // [2][64][128]
{
    const int bid = blockIdx.x;
    const int dir = bid >> 6;
    const int b = bid & 63;
    const int t = threadIdx.x;
    const int lane = t & 63, wv = t >> 6;
    const int gtype = wv >> 1;
    const float* Whh = dir ? Whh_b : Whh_f;
    const int len = lengths[b];

    float wr[128];
#pragma unroll
    for (int i = 0; i < 128; i += 4) {
        float4 v = *(const float4*)(Whh + t * 128 + i);
        wr[i] = v.x; wr[i + 1] = v.y; wr[i + 2] = v.z; wr[i + 3] = v.w;
    }

    __shared__ float gact[2][512];
    float h0 = 0.f, h1 = 0.f, c0 = 0.f, c1 = 0.f;
    const float* xpp = xp + ((size_t)dir * 4096 + b) * 512 + t;

    for (int l = 0; l < 64; l++) {
        float xg = xpp[(size_t)l * 32768];
        float a0 = xg, a1 = 0.f, a2 = 0.f, a3 = 0.f;
#pragma unroll
        for (int j = 0; j < 64; j += 2) {
            a0 = fmaf(wr[j], rl(h0, j), a0);
            a1 = fmaf(wr[j + 1], rl(h0, j + 1), a1);
        }
#pragma unroll
        for (int j = 0; j < 64; j += 2) {
            a2 = fmaf(wr[64 + j], rl(h1, j), a2);
            a3 = fmaf(wr[64 + j + 1], rl(h1, j + 1), a3);
        }
        float acc = (a0 + a1) + (a2 + a3);
        float act = (gtype == 2) ? ftanh(acc) : fsigmoid(acc);
        gact[l & 1][t] = act;
        __syncthreads();
        float iv0 = gact[l & 1][lane],       iv1 = gact[l & 1][64 + lane];
        float fv0 = gact[l & 1][128 + lane], fv1 = gact[l & 1][192 + lane];
        float gv0 = gact[l & 1][256 + lane], gv1 = gact[l & 1][320 + lane];
        float ov0 = gact[l & 1][384 + lane], ov1 = gact[l & 1][448 + lane];
        float cn0 = fv0 * c0 + iv0 * gv0;
        float cn1 = fv1 * c1 + iv1 * gv1;
        float hn0 = ov0 * ftanh(cn0);
        float hn1 = ov1 * ftanh(cn1);
        bool upd = ((dir == 0) ? l : (63 - l)) < len;
        if (upd) { c0 = cn0; c1 = cn1; h0 = hn0; h1 = hn1; }
    }
    if (wv == 0) {
        hfin[((size_t)dir * 64 + b) * 128 + lane] = h0;
        hfin[((size_t)dir * 64 + b) * 128 + 64 + lane] = h1;
    }
}

__global__ void fc_k(const float* __restrict__ hf, const float* __restrict__ Wfc,
                     const float* __restrict__ bfc, float* __restrict__ out) {
    int t = threadIdx.x;
    int b = t >> 2, c = t & 3;
    float s = bfc[c];
#pragma unroll 4
    for (int j = 0; j < 128; j++) s = fmaf(hf[b * 128 + j], Wfc[c * 256 + j], s);
#pragma unroll 4
    for (int j = 0; j < 128; j++) s = fmaf(hf[(64 + b) * 128 + j], Wfc[c * 256 + 128 + j], s);
    out[b * 4 + c] = s;
}

extern "C" void kernel_launch(void* const* d_in, const int* in_sizes, int n_in,
                              void* d_out, int out_size, void* d_ws, size_t ws_size,
                              hipStream_t stream) {
    const float* A     = (const float*)d_in[0];
    const float* X     = (const float*)d_in[1];
    const int*   tok   = (const int*)d_in[2];
    const int*   lens  = (const int*)d_in[3];
    const float* W1    = (const float*)d_in[4];
    const float* b1    = (const float*)d_in[5];
    const float* W2    = (const float*)d_in[6];
    const float* b2    = (const float*)d_in[7];
    const float* Wih_f = (const float*)d_in[8];
    const float* Whh_f = (const float*)d_in[9];
    const float* b_f   = (const float*)d_in[10];
    const float* Wih_b = (const float*)d_in[11];
    const float* Whh_b = (const float*)d_in[12];
    const float* b_b   = (const float*)d_in[13];
    const float* Wfc   = (const float*)d_in[14];
    const float* bfc   = (const float*)d_in[15];
    float* out = (float*)d_out;
    char* ws = (char*)d_ws;

    // workspace map (bytes)
    float* H1p  = (float*)(ws + 0);              // [4][8192][256] = 32 MB
    float* xp   = (float*)(ws + 0);              // [2][64][64][512] = 16 MB (after K3)
    u16*   B1hi = (u16*)(ws + 33554432);         // [256][256][32] = 4 MB
    u16*   B1lo = (u16*)(ws + 37748736);
    u16*   B2hi = (u16*)(ws + 41943040);         // [256][128][32] = 2 MB
    u16*   B2lo = (u16*)(ws + 44040192);
    float* sqP  = (float*)(ws + 46137344);       // [16][4096][128] = 32 MB
    float* hfin = (float*)(ws + 79691776);       // 64 KB
    u16*   W1h  = (u16*)(ws + 79757312);         // [8][256][32] = 128 KB
    u16*   W1l  = (u16*)(ws + 79888384);
    u16*   W2h  = (u16*)(ws + 80019456);         // [8][128][32] = 64 KB
    u16*   W2l  = (u16*)(ws + 80084992);
    u16*   Wfh  = (u16*)(ws + 80150528);         // [4][512][32] = 128 KB
    u16*   Wfl  = (u16*)(ws + 80281600);
    u16*   Wbh  = (u16*)(ws + 80412672);
    u16*   Wbl  = (u16*)(ws + 80543744);

    wsplit_k<1><<<32, 256, 0, stream>>>(W1, W1h, W1l, 256, 256);
    wsplit_k<1><<<16, 256, 0, stream>>>(W2, W2h, W2l, 256, 128);
    wsplit_k<0><<<32, 256, 0, stream>>>(Wih_f, Wfh, Wfl, 128, 512);
    wsplit_k<0><<<32, 256, 0, stream>>>(Wih_b, Wbh, Wbl, 128, 512);

    // K1: B1 = swizzle_split(X @ W1)    grid (32 m, 1, 2 n)
    gemm2_k<0, 1, 0, 1, 0, 0><<<dim3(32, 1, 2), 512, 0, stream>>>(
        X, 256, 8192, W1h, W1l, nullptr, nullptr, 256,
        nullptr, 0, 0, B1hi, B1lo, 256,
        nullptr, nullptr, nullptr, nullptr, 256, 4096);
    // K2: H1p[s] = A @ B1 (split-K 4)   grid (32 m, 4 k, 2 n)
    gemm2_k<0, 1, 0, 0, 0, 0><<<dim3(32, 4, 2), 512, 0, stream>>>(
        A, 8192, 8192, B1hi, B1lo, nullptr, nullptr, 256,
        H1p, 256, (long)8192 * 256, nullptr, nullptr, 0,
        nullptr, nullptr, nullptr, nullptr, 2048, 4096);
    // K3: B2 = swizzle_split((sum H1p + b1) @ W2)   grid (32, 1, 1)
    gemm2_k<0, 4, 1, 1, 0, 0><<<dim3(32, 1, 1), 512, 0, stream>>>(
        H1p, 256, 8192, W2h, W2l, nullptr, nullptr, 128,
        nullptr, 0, 0, B2hi, B2lo, 128,
        b1, nullptr, nullptr, nullptr, 256, 4096);
    // K4: sqP[s] = A[tok] @ B2 (split-K 16)   grid (16 m, 16 k, 1)
    gemm2_k<1, 1, 0, 0, 0, 0><<<dim3(16, 16, 1), 512, 0, stream>>>(
        A, 8192, 8192, B2hi, B2lo, nullptr, nullptr, 128,
        sqP, 128, (long)4096 * 128, nullptr, nullptr, 0,
        nullptr, nullptr, nullptr, tok, 512, 4096);
    // K5: xp = (sum sqP + b2)[trip] @ Wih^T + b   grid (32 m, 1, 4 n)
    gemm2_k<2, 16, 1, 0, 1, 1><<<dim3(32, 1, 4), 512, 0, stream>>>(
        sqP, 128, 4096, Wfh, Wfl, Wbh, Wbl, 512,
        xp, 512, 0, nullptr, nullptr, 0,
        b2, b_f, b_b, nullptr, 128, 4096);
    // K6: BiLSTM
    lstm_k<<<128, 512, 0, stream>>>(xp, Whh_f, Whh_b, lens, hfin);
    // K7: final FC
    fc_k<<<1, 256, 0, stream>>>(hfin, Wfc, bfc, out);
}